// Round 1
// baseline (325.812 us; speedup 1.0000x reference)
//
#include <hip/hip_runtime.h>
#include <hip/hip_bf16.h>
#include <cmath>

// ---------------------------------------------------------------------------
// Causal single-head self-attention, B=4 T=2048 C=1024, fp32 in/out,
// bf16 MFMA internally (threshold is bf16-calibrated: 8*eps floor).
// Everything is reduced to one GEMM shape: C[m][n] = sum_k A[m][k]*Bt[n][k]
// (both operands row-major with contiguous K) — the m97-verified structure.
// ---------------------------------------------------------------------------

typedef __attribute__((ext_vector_type(8))) __bf16 bf16x8;
typedef __attribute__((ext_vector_type(8))) short short8;
typedef __attribute__((ext_vector_type(4))) float f32x4;

__device__ __forceinline__ unsigned short f2bf(float f) {
  union { float f; unsigned u; } v; v.f = f;
  unsigned u = v.u;
  u += ((u >> 16) & 1u) + 0x7fffu;   // round-to-nearest-even
  return (unsigned short)(u >> 16);
}
__device__ __forceinline__ float bf2f(unsigned short h) {
  union { unsigned u; float f; } v; v.u = ((unsigned)h) << 16;
  return v.f;
}

#define GLDS(gp, sp)                                                           \
  __builtin_amdgcn_global_load_lds(                                            \
      (const __attribute__((address_space(1))) void*)(gp),                     \
      (__attribute__((address_space(3))) void*)(sp), 16, 0, 0)

// -------------------------- cast X fp32 -> bf16 ----------------------------
__global__ void cast_kernel(const float* __restrict__ src,
                            unsigned short* __restrict__ dst, int n) {
  int i = (blockIdx.x * blockDim.x + threadIdx.x) * 4;
  if (i >= n) return;
  float4 f = *(const float4*)(src + i);
  ushort4 o = make_ushort4(f2bf(f.x), f2bf(f.y), f2bf(f.z), f2bf(f.w));
  *(ushort4*)(dst + i) = o;
}

// --------------------- transpose + cast fp32 -> bf16 -----------------------
// dst[c][r] = src[r][c]
__global__ void transpose_cast(const float* __restrict__ src,
                               unsigned short* __restrict__ dst,
                               int rows, int cols) {
  __shared__ float tile[32][33];
  int bx = blockIdx.x * 32;  // col base
  int by = blockIdx.y * 32;  // row base
  int tx = threadIdx.x;      // 0..31
  int ty = threadIdx.y;      // 0..7
#pragma unroll
  for (int i = 0; i < 32; i += 8)
    tile[ty + i][tx] = src[(size_t)(by + ty + i) * cols + bx + tx];
  __syncthreads();
#pragma unroll
  for (int i = 0; i < 32; i += 8)
    dst[(size_t)(bx + ty + i) * rows + by + tx] = f2bf(tile[tx][ty + i]);
}

// ------------------------------ GEMM (B^T) ---------------------------------
// C[m][n] = alpha * sum_k A[m][k] * Bt[n][k]
// 128x128 tile, BK=64, 256 threads (4 waves, 2x2 of 64x64), 16x16x32 bf16 MFMA.
// All of M, N divisible by 128; K divisible by 64 (true for every call here).
template <typename OutT>
__global__ __launch_bounds__(256, 2)
void gemm_bt(const unsigned short* __restrict__ A, int lda, long long sA,
             const unsigned short* __restrict__ B, int ldb, long long sB,
             OutT* __restrict__ Cp, int ldc, long long sC,
             int K, float alpha) {
  A  += (long long)blockIdx.z * sA;
  B  += (long long)blockIdx.z * sB;
  Cp += (long long)blockIdx.z * sC;

  const int m0   = blockIdx.y * 128;
  const int n0   = blockIdx.x * 128;
  const int tid  = threadIdx.x;
  const int lane = tid & 63;
  const int w    = tid >> 6;
  const int wm   = (w >> 1) * 64;
  const int wn   = (w & 1) * 64;
  const int quad = lane >> 4;
  const int l16  = lane & 15;

  __shared__ unsigned short As[128 * 64];
  __shared__ unsigned short Bs[128 * 64];

  f32x4 acc[4][4];
#pragma unroll
  for (int i = 0; i < 4; ++i)
#pragma unroll
    for (int j = 0; j < 4; ++j)
      acc[i][j] = (f32x4){0.f, 0.f, 0.f, 0.f};

  // staging: 256 thr x 16B = 4KB/round = 32 rows x 64 bf16; 4 rounds per tile.
  // LDS dest = wave-uniform base + lane*16 (global_load_lds constraint):
  // byte offset (r*2048 + tid*8)*2 = r*4096 + w*1024 + lane*16.  OK.
  const int srow = tid >> 3;
  const int scol = (tid & 7) * 8;
  const unsigned short* gA = A + (long long)(m0 + srow) * lda + scol;
  const unsigned short* gB = B + (long long)(n0 + srow) * ldb + scol;

  for (int kt = 0; kt < K; kt += 64) {
    __syncthreads();  // previous iter's ds_reads done before overwrite
#pragma unroll
    for (int r = 0; r < 4; ++r) {
      GLDS(gA + (long long)(r * 32) * lda + kt, As + r * 2048 + tid * 8);
      GLDS(gB + (long long)(r * 32) * ldb + kt, Bs + r * 2048 + tid * 8);
    }
    __syncthreads();  // compiler drains vmcnt before barrier
#pragma unroll
    for (int ks = 0; ks < 2; ++ks) {
      bf16x8 af[4], bfr[4];
#pragma unroll
      for (int i = 0; i < 4; ++i)
        af[i] = *(const bf16x8*)(As + (wm + i * 16 + l16) * 64 + ks * 32 + quad * 8);
#pragma unroll
      for (int j = 0; j < 4; ++j)
        bfr[j] = *(const bf16x8*)(Bs + (wn + j * 16 + l16) * 64 + ks * 32 + quad * 8);
#pragma unroll
      for (int i = 0; i < 4; ++i)
#pragma unroll
        for (int j = 0; j < 4; ++j)
          acc[i][j] = __builtin_amdgcn_mfma_f32_16x16x32_bf16(af[i], bfr[j],
                                                              acc[i][j], 0, 0, 0);
    }
  }

  // C/D layout (m89/m91 verified): col = lane&15, row = quad*4 + reg
#pragma unroll
  for (int i = 0; i < 4; ++i) {
#pragma unroll
    for (int j = 0; j < 4; ++j) {
#pragma unroll
      for (int r = 0; r < 4; ++r) {
        const int row = m0 + wm + i * 16 + quad * 4 + r;
        const int col = n0 + wn + j * 16 + l16;
        float v = acc[i][j][r] * alpha;
        if constexpr (sizeof(OutT) == 2)
          Cp[(long long)row * ldc + col] = (OutT)f2bf(v);
        else
          Cp[(long long)row * ldc + col] = v;
      }
    }
  }
}

// ------------------------- causal softmax (in place) -----------------------
// One block per score row (bf16, length T). Row index t = row % T; s>t masked.
__global__ __launch_bounds__(256)
void softmax_causal(unsigned short* __restrict__ S, int T) {
  const long long row = blockIdx.x;
  const int t = (int)(row & (long long)(T - 1));
  unsigned short* p = S + row * T;
  const int tid  = threadIdx.x;
  const int base = tid * 8;

  short8 raw = *(const short8*)(p + base);
  float x[8];
  float mx = -1e30f;
#pragma unroll
  for (int j = 0; j < 8; ++j) {
    bool valid = (base + j) <= t;
    x[j] = valid ? bf2f((unsigned short)raw[j]) : -1e30f;
    mx = fmaxf(mx, x[j]);
  }
#pragma unroll
  for (int off = 32; off > 0; off >>= 1) mx = fmaxf(mx, __shfl_xor(mx, off));
  __shared__ float red[8];
  const int wv = tid >> 6;
  if ((tid & 63) == 0) red[wv] = mx;
  __syncthreads();
  mx = fmaxf(fmaxf(red[0], red[1]), fmaxf(red[2], red[3]));

  float sum = 0.f;
#pragma unroll
  for (int j = 0; j < 8; ++j) {
    bool valid = (base + j) <= t;
    x[j] = valid ? __expf(x[j] - mx) : 0.f;
    sum += x[j];
  }
#pragma unroll
  for (int off = 32; off > 0; off >>= 1) sum += __shfl_xor(sum, off);
  if ((tid & 63) == 0) red[4 + wv] = sum;
  __syncthreads();
  sum = red[4] + red[5] + red[6] + red[7];
  const float inv = 1.f / sum;

  unsigned short out[8];
#pragma unroll
  for (int j = 0; j < 8; ++j) out[j] = f2bf(x[j] * inv);
  *(short8*)(p + base) = *(const short8*)out;
}

// ---------------------------------------------------------------------------
extern "C" void kernel_launch(void* const* d_in, const int* in_sizes, int n_in,
                              void* d_out, int out_size, void* d_ws,
                              size_t ws_size, hipStream_t stream) {
  (void)in_sizes; (void)n_in; (void)out_size; (void)ws_size;
  const int Bb = 4, T = 2048, C = 1024;
  const int M = Bb * T;  // 8192

  const float* X  = (const float*)d_in[0];
  const float* Wq = (const float*)d_in[1];
  const float* Wk = (const float*)d_in[2];
  const float* Wv = (const float*)d_in[3];
  const float* Wo = (const float*)d_in[4];
  float* Out = (float*)d_out;

  // workspace carve (bf16 everywhere): 72 MB total
  char* w = (char*)d_ws;
  unsigned short* Xb  = (unsigned short*)w; w += (size_t)M * C * 2;  // 16MB
  unsigned short* Wqt = (unsigned short*)w; w += (size_t)C * C * 2;  // 2MB
  unsigned short* Wkt = (unsigned short*)w; w += (size_t)C * C * 2;
  unsigned short* Wvt = (unsigned short*)w; w += (size_t)C * C * 2;
  unsigned short* Wot = (unsigned short*)w; w += (size_t)C * C * 2;
  unsigned short* Q   = (unsigned short*)w; w += (size_t)M * C * 2;  // 16MB
  unsigned short* Kb  = (unsigned short*)w; w += (size_t)M * C * 2;  // 16MB
  unsigned short* Vt  = (unsigned short*)w; w += (size_t)M * C * 2;  // 16MB [B][C][T]
  unsigned short* O   = Xb;  // alias: Xb dead after Vt GEMM, O written after
  // S lives in d_out: 4*2048*2048*2 B == out bytes; dead before final GEMM
  unsigned short* S   = (unsigned short*)d_out;

  // 1) casts / transposes
  cast_kernel<<<(M * C) / 4 / 256, 256, 0, stream>>>(X, Xb, M * C);
  dim3 tb(32, 8), tg(C / 32, C / 32);
  transpose_cast<<<tg, tb, 0, stream>>>(Wq, Wqt, C, C);
  transpose_cast<<<tg, tb, 0, stream>>>(Wk, Wkt, C, C);
  transpose_cast<<<tg, tb, 0, stream>>>(Wv, Wvt, C, C);
  transpose_cast<<<tg, tb, 0, stream>>>(Wo, Wot, C, C);

  dim3 blk(256);
  // 2) Q = Xb @ Wq   (Bt = Wq^T)
  gemm_bt<unsigned short><<<dim3(C / 128, M / 128, 1), blk, 0, stream>>>(
      Xb, C, 0, Wqt, C, 0, Q, C, 0, C, 1.f);
  // 3) K = Xb @ Wk
  gemm_bt<unsigned short><<<dim3(C / 128, M / 128, 1), blk, 0, stream>>>(
      Xb, C, 0, Wkt, C, 0, Kb, C, 0, C, 1.f);
  // 4) Vt[b] = Wv^T @ Xb[b]^T  (M=C rows of Wvt, N=T rows of Xb[b])
  gemm_bt<unsigned short><<<dim3(T / 128, C / 128, Bb), blk, 0, stream>>>(
      Wvt, C, 0, Xb, C, (long long)T * C, Vt, T, (long long)C * T, C, 1.f);
  // 5) S[b] = Q[b] @ K[b]^T / 32
  gemm_bt<unsigned short><<<dim3(T / 128, T / 128, Bb), blk, 0, stream>>>(
      Q, C, (long long)T * C, Kb, C, (long long)T * C,
      S, T, (long long)T * T, C, 0.03125f);
  // 6) causal softmax rows (in place, bf16)
  softmax_causal<<<M, 256, 0, stream>>>(S, T);
  // 7) O[b] = P[b] @ V[b]   (Bt = Vt[b])
  gemm_bt<unsigned short><<<dim3(C / 128, T / 128, Bb), blk, 0, stream>>>(
      S, T, (long long)T * T, Vt, T, (long long)C * T,
      O, C, (long long)T * C, T, 1.f);
  // 8) Out = O @ Wo  (fp32 epilogue into d_out)
  gemm_bt<float><<<dim3(C / 128, M / 128, 1), blk, 0, stream>>>(
      O, C, 0, Wot, C, 0, Out, C, 0, C, 1.f);
}

// Round 2
// 288.783 us; speedup vs baseline: 1.1282x; 1.1282x over previous
//
#include <hip/hip_runtime.h>
#include <hip/hip_bf16.h>
#include <cmath>

// ---------------------------------------------------------------------------
// Causal single-head self-attention, B=4 T=2048 C=1024, fp32 in/out,
// bf16 MFMA internally. One GEMM shape: C[m][n] = sum_k A[m][k]*Bt[n][k].
// R1: LDS xor-swizzle (kills 1.26e7 bank conflicts), causal tile skipping
// in S GEMM, causal K-truncation in PV GEMM, softmax row truncation.
// ---------------------------------------------------------------------------

typedef __attribute__((ext_vector_type(8))) __bf16 bf16x8;
typedef __attribute__((ext_vector_type(8))) short short8;
typedef __attribute__((ext_vector_type(4))) float f32x4;

__device__ __forceinline__ unsigned short f2bf(float f) {
  union { float f; unsigned u; } v; v.f = f;
  unsigned u = v.u;
  u += ((u >> 16) & 1u) + 0x7fffu;   // round-to-nearest-even
  return (unsigned short)(u >> 16);
}
__device__ __forceinline__ float bf2f(unsigned short h) {
  union { unsigned u; float f; } v; v.u = ((unsigned)h) << 16;
  return v.f;
}

#define GLDS(gp, sp)                                                           \
  __builtin_amdgcn_global_load_lds(                                            \
      (const __attribute__((address_space(1))) void*)(gp),                     \
      (__attribute__((address_space(3))) void*)(sp), 16, 0, 0)

// -------------------------- cast X fp32 -> bf16 ----------------------------
__global__ void cast_kernel(const float* __restrict__ src,
                            unsigned short* __restrict__ dst, int n) {
  int i = (blockIdx.x * blockDim.x + threadIdx.x) * 4;
  if (i >= n) return;
  float4 f = *(const float4*)(src + i);
  ushort4 o = make_ushort4(f2bf(f.x), f2bf(f.y), f2bf(f.z), f2bf(f.w));
  *(ushort4*)(dst + i) = o;
}

// --------------------- transpose + cast fp32 -> bf16 -----------------------
__global__ void transpose_cast(const float* __restrict__ src,
                               unsigned short* __restrict__ dst,
                               int rows, int cols) {
  __shared__ float tile[32][33];
  int bx = blockIdx.x * 32;  // col base
  int by = blockIdx.y * 32;  // row base
  int tx = threadIdx.x;      // 0..31
  int ty = threadIdx.y;      // 0..7
#pragma unroll
  for (int i = 0; i < 32; i += 8)
    tile[ty + i][tx] = src[(size_t)(by + ty + i) * cols + bx + tx];
  __syncthreads();
#pragma unroll
  for (int i = 0; i < 32; i += 8)
    dst[(size_t)(bx + ty + i) * rows + by + tx] = f2bf(tile[tx][ty + i]);
}

// ------------------------------ GEMM (B^T) ---------------------------------
// C[m][n] = alpha * sum_k A[m][k] * Bt[n][k]
// 128x128 tile, BK=64, 256 threads (4 waves, 2x2 of 64x64), 16x16x32 bf16 MFMA.
// LDS swizzle: lane fetches global chunk (c ^ (row&7)) into LDS chunk c, so a
// fragment read of global chunk g of row r reads LDS chunk g^(r&7) — spreads
// the quad's 16 lanes across all 8 chunk-columns (32 banks). Conflict-free.
// tri  != 0 : decode blockIdx.x as lower-triangular (by,bx) tile index.
// kcap != 0 : K_eff = min(K, m0+128) (causal PV truncation).
template <typename OutT>
__global__ __launch_bounds__(256, 2)
void gemm_bt(const unsigned short* __restrict__ A, int lda, long long sA,
             const unsigned short* __restrict__ B, int ldb, long long sB,
             OutT* __restrict__ Cp, int ldc, long long sC,
             int K, float alpha, int tri, int kcap) {
  A  += (long long)blockIdx.z * sA;
  B  += (long long)blockIdx.z * sB;
  Cp += (long long)blockIdx.z * sC;

  int by, bx;
  if (tri) {
    const int idx = blockIdx.x;
    by = (int)((sqrtf(8.f * idx + 1.f) - 1.f) * 0.5f);
    while (by * (by + 1) / 2 > idx) --by;
    while ((by + 1) * (by + 2) / 2 <= idx) ++by;
    bx = idx - by * (by + 1) / 2;
  } else {
    by = blockIdx.y;
    bx = blockIdx.x;
  }
  const int m0 = by * 128;
  const int n0 = bx * 128;
  const int Keff = kcap ? min(K, m0 + 128) : K;

  const int tid  = threadIdx.x;
  const int lane = tid & 63;
  const int w    = tid >> 6;
  const int wm   = (w >> 1) * 64;
  const int wn   = (w & 1) * 64;
  const int quad = lane >> 4;
  const int l16  = lane & 15;

  __shared__ unsigned short As[128 * 64];
  __shared__ unsigned short Bs[128 * 64];

  f32x4 acc[4][4];
#pragma unroll
  for (int i = 0; i < 4; ++i)
#pragma unroll
    for (int j = 0; j < 4; ++j)
      acc[i][j] = (f32x4){0.f, 0.f, 0.f, 0.f};

  // staging: 256 thr x 16B = 4KB/round = 32 rows x 64 bf16; 4 rounds/tile.
  // swizzled global chunk col: ((tid&7) ^ (srow&7)) * 8 elements.
  const int srow = tid >> 3;
  const int scol = ((tid & 7) ^ (srow & 7)) * 8;
  const unsigned short* gA = A + (long long)(m0 + srow) * lda + scol;
  const unsigned short* gB = B + (long long)(n0 + srow) * ldb + scol;
  const int rsw = l16 & 7;  // row&7 for all fragment rows (wm,i*16 ≡ 0 mod 8)

  for (int kt = 0; kt < Keff; kt += 64) {
    __syncthreads();
#pragma unroll
    for (int r = 0; r < 4; ++r) {
      GLDS(gA + (long long)(r * 32) * lda + kt, As + r * 2048 + tid * 8);
      GLDS(gB + (long long)(r * 32) * ldb + kt, Bs + r * 2048 + tid * 8);
    }
    __syncthreads();
#pragma unroll
    for (int ks = 0; ks < 2; ++ks) {
      bf16x8 af[4], bfr[4];
#pragma unroll
      for (int i = 0; i < 4; ++i)
        af[i] = *(const bf16x8*)(As + (wm + i * 16 + l16) * 64 +
                                 ((ks * 4 + quad) ^ rsw) * 8);
#pragma unroll
      for (int j = 0; j < 4; ++j)
        bfr[j] = *(const bf16x8*)(Bs + (wn + j * 16 + l16) * 64 +
                                  ((ks * 4 + quad) ^ rsw) * 8);
#pragma unroll
      for (int i = 0; i < 4; ++i)
#pragma unroll
        for (int j = 0; j < 4; ++j)
          acc[i][j] = __builtin_amdgcn_mfma_f32_16x16x32_bf16(af[i], bfr[j],
                                                              acc[i][j], 0, 0, 0);
    }
  }

  // C/D layout (m89/m91 verified): col = lane&15, row = quad*4 + reg
#pragma unroll
  for (int i = 0; i < 4; ++i) {
#pragma unroll
    for (int j = 0; j < 4; ++j) {
#pragma unroll
      for (int r = 0; r < 4; ++r) {
        const int row = m0 + wm + i * 16 + quad * 4 + r;
        const int col = n0 + wn + j * 16 + l16;
        float v = acc[i][j][r] * alpha;
        if constexpr (sizeof(OutT) == 2)
          Cp[(long long)row * ldc + col] = (OutT)f2bf(v);
        else
          Cp[(long long)row * ldc + col] = v;
      }
    }
  }
}

// ------------------------- causal softmax (in place) -----------------------
// One block per score row (bf16, length T). Row index t = row % T.
// Only columns < limit = roundup(t+1,128) are touched (PV reads exactly those).
__global__ __launch_bounds__(256)
void softmax_causal(unsigned short* __restrict__ S, int T) {
  const long long row = blockIdx.x;
  const int t = (int)(row & (long long)(T - 1));
  const int limit = ((t >> 7) + 1) << 7;
  unsigned short* p = S + row * T;
  const int tid  = threadIdx.x;
  const int base = tid * 8;
  const bool active = base < limit;

  short8 raw = {};
  if (active) raw = *(const short8*)(p + base);
  float x[8];
  float mx = -1e30f;
#pragma unroll
  for (int j = 0; j < 8; ++j) {
    bool valid = active && (base + j) <= t;
    x[j] = valid ? bf2f((unsigned short)raw[j]) : -1e30f;
    mx = fmaxf(mx, x[j]);
  }
#pragma unroll
  for (int off = 32; off > 0; off >>= 1) mx = fmaxf(mx, __shfl_xor(mx, off));
  __shared__ float red[8];
  const int wv = tid >> 6;
  if ((tid & 63) == 0) red[wv] = mx;
  __syncthreads();
  mx = fmaxf(fmaxf(red[0], red[1]), fmaxf(red[2], red[3]));

  float sum = 0.f;
#pragma unroll
  for (int j = 0; j < 8; ++j) {
    bool valid = active && (base + j) <= t;
    x[j] = valid ? __expf(x[j] - mx) : 0.f;
    sum += x[j];
  }
#pragma unroll
  for (int off = 32; off > 0; off >>= 1) sum += __shfl_xor(sum, off);
  if ((tid & 63) == 0) red[4 + wv] = sum;
  __syncthreads();
  sum = red[4] + red[5] + red[6] + red[7];
  const float inv = 1.f / sum;

  if (active) {
    unsigned short out[8];
#pragma unroll
    for (int j = 0; j < 8; ++j) out[j] = f2bf(x[j] * inv);
    *(short8*)(p + base) = *(const short8*)out;
  }
}

// ---------------------------------------------------------------------------
extern "C" void kernel_launch(void* const* d_in, const int* in_sizes, int n_in,
                              void* d_out, int out_size, void* d_ws,
                              size_t ws_size, hipStream_t stream) {
  (void)in_sizes; (void)n_in; (void)out_size; (void)ws_size;
  const int Bb = 4, T = 2048, C = 1024;
  const int M = Bb * T;  // 8192

  const float* X  = (const float*)d_in[0];
  const float* Wq = (const float*)d_in[1];
  const float* Wk = (const float*)d_in[2];
  const float* Wv = (const float*)d_in[3];
  const float* Wo = (const float*)d_in[4];
  float* Out = (float*)d_out;

  char* w = (char*)d_ws;
  unsigned short* Xb  = (unsigned short*)w; w += (size_t)M * C * 2;  // 16MB
  unsigned short* Wqt = (unsigned short*)w; w += (size_t)C * C * 2;  // 2MB
  unsigned short* Wkt = (unsigned short*)w; w += (size_t)C * C * 2;
  unsigned short* Wvt = (unsigned short*)w; w += (size_t)C * C * 2;
  unsigned short* Wot = (unsigned short*)w; w += (size_t)C * C * 2;
  unsigned short* Q   = (unsigned short*)w; w += (size_t)M * C * 2;  // 16MB
  unsigned short* Kb  = (unsigned short*)w; w += (size_t)M * C * 2;  // 16MB
  unsigned short* Vt  = (unsigned short*)w; w += (size_t)M * C * 2;  // 16MB [B][C][T]
  unsigned short* O   = Xb;  // alias: Xb dead after Vt GEMM
  unsigned short* S   = (unsigned short*)d_out;  // 32MB, dead before final GEMM

  cast_kernel<<<(M * C) / 4 / 256, 256, 0, stream>>>(X, Xb, M * C);
  dim3 tb(32, 8), tg(C / 32, C / 32);
  transpose_cast<<<tg, tb, 0, stream>>>(Wq, Wqt, C, C);
  transpose_cast<<<tg, tb, 0, stream>>>(Wk, Wkt, C, C);
  transpose_cast<<<tg, tb, 0, stream>>>(Wv, Wvt, C, C);
  transpose_cast<<<tg, tb, 0, stream>>>(Wo, Wot, C, C);

  dim3 blk(256);
  // Q = Xb @ Wq^T-layout
  gemm_bt<unsigned short><<<dim3(C / 128, M / 128, 1), blk, 0, stream>>>(
      Xb, C, 0, Wqt, C, 0, Q, C, 0, C, 1.f, 0, 0);
  // K = Xb @ Wk
  gemm_bt<unsigned short><<<dim3(C / 128, M / 128, 1), blk, 0, stream>>>(
      Xb, C, 0, Wkt, C, 0, Kb, C, 0, C, 1.f, 0, 0);
  // Vt[b] = Wv^T @ Xb[b]^T
  gemm_bt<unsigned short><<<dim3(T / 128, C / 128, Bb), blk, 0, stream>>>(
      Wvt, C, 0, Xb, C, (long long)T * C, Vt, T, (long long)C * T, C, 1.f, 0, 0);
  // S[b] = Q[b] @ K[b]^T / 32 — lower-triangle tiles only (136 of 256)
  const int ntri = (T / 128) * (T / 128 + 1) / 2;
  gemm_bt<unsigned short><<<dim3(ntri, 1, Bb), blk, 0, stream>>>(
      Q, C, (long long)T * C, Kb, C, (long long)T * C,
      S, T, (long long)T * T, C, 0.03125f, 1, 0);
  // causal softmax (row-truncated)
  softmax_causal<<<M, 256, 0, stream>>>(S, T);
  // O[b] = P[b] @ V[b] with causal K-cap
  gemm_bt<unsigned short><<<dim3(C / 128, T / 128, Bb), blk, 0, stream>>>(
      S, T, (long long)T * T, Vt, T, (long long)C * T,
      O, C, (long long)T * C, T, 1.f, 0, 1);
  // Out = O @ Wo (fp32 epilogue)
  gemm_bt<float><<<dim3(C / 128, M / 128, 1), blk, 0, stream>>>(
      O, C, 0, Wot, C, 0, Out, C, 0, C, 1.f, 0, 0);
}

// Round 3
// 274.866 us; speedup vs baseline: 1.1853x; 1.0506x over previous
//
#include <hip/hip_runtime.h>
#include <hip/hip_bf16.h>
#include <cmath>

// ---------------------------------------------------------------------------
// Causal single-head self-attention, B=4 T=2048 C=1024, fp32 in/out,
// bf16 MFMA internally. One GEMM shape: C[m][n] = sum_k A[m][k]*Bt[n][k].
// R1: LDS xor-swizzle (conflicts 1.26e7 -> 0), causal tile skip + K-cap.
// R2: fused QKV projection (N=3072, V stored transposed in epilogue) and
//     XCD-aware block swizzle (8-row groups, x-major) for L2 A-tile reuse.
// ---------------------------------------------------------------------------

typedef __attribute__((ext_vector_type(8))) __bf16 bf16x8;
typedef __attribute__((ext_vector_type(8))) short short8;
typedef __attribute__((ext_vector_type(4))) float f32x4;

__device__ __forceinline__ unsigned short f2bf(float f) {
  union { float f; unsigned u; } v; v.f = f;
  unsigned u = v.u;
  u += ((u >> 16) & 1u) + 0x7fffu;   // round-to-nearest-even
  return (unsigned short)(u >> 16);
}
__device__ __forceinline__ float bf2f(unsigned short h) {
  union { unsigned u; float f; } v; v.u = ((unsigned)h) << 16;
  return v.f;
}

#define GLDS(gp, sp)                                                           \
  __builtin_amdgcn_global_load_lds(                                            \
      (const __attribute__((address_space(1))) void*)(gp),                     \
      (__attribute__((address_space(3))) void*)(sp), 16, 0, 0)

// -------------------------- cast X fp32 -> bf16 ----------------------------
__global__ void cast_kernel(const float* __restrict__ src,
                            unsigned short* __restrict__ dst, int n) {
  int i = (blockIdx.x * blockDim.x + threadIdx.x) * 4;
  if (i >= n) return;
  float4 f = *(const float4*)(src + i);
  ushort4 o = make_ushort4(f2bf(f.x), f2bf(f.y), f2bf(f.z), f2bf(f.w));
  *(ushort4*)(dst + i) = o;
}

// ----------------- transpose + cast all 4 weights (z selects) --------------
__global__ void transpose4(const float* __restrict__ w0,
                           const float* __restrict__ w1,
                           const float* __restrict__ w2,
                           const float* __restrict__ w3,
                           unsigned short* __restrict__ wcat,  // [3C][C]
                           unsigned short* __restrict__ wot,   // [C][C]
                           int n) {
  const float* src = blockIdx.z == 0 ? w0 : blockIdx.z == 1 ? w1
                     : blockIdx.z == 2 ? w2 : w3;
  unsigned short* dst = blockIdx.z < 3 ? wcat + (size_t)blockIdx.z * n * n : wot;
  __shared__ float tile[32][33];
  int bx = blockIdx.x * 32, by = blockIdx.y * 32;
  int tx = threadIdx.x, ty = threadIdx.y;
#pragma unroll
  for (int i = 0; i < 32; i += 8)
    tile[ty + i][tx] = src[(size_t)(by + ty + i) * n + bx + tx];
  __syncthreads();
#pragma unroll
  for (int i = 0; i < 32; i += 8)
    dst[(size_t)(bx + ty + i) * n + by + tx] = f2bf(tile[tx][ty + i]);
}

// ------------------------------ GEMM (B^T) ---------------------------------
// C[m][n] = alpha * sum_k A[m][k] * Bt[n][k]
// 128x128 tile, BK=64, 256 threads (4 waves, 2x2 of 64x64), 16x16x32 bf16 MFMA.
// LDS xor-swizzle keeps all fragment reads conflict-free (R1-verified).
// tri : blockIdx.x is a lower-triangular tile index.
// kcap: K_eff = min(K, m0+128) (causal PV truncation).
// gx>0: 1D grid, XCD-aware decode — groups of 8 by-rows, bx-major inside a
//       group, yy fastest so id%8 (the XCD) pins one A-row-tile per XCD.
// qkv : fused projection epilogue. Cp = Q base; K at +8M elems; V at +16M,
//       written transposed as Vt[b][c][t] (t = row % 2048).
template <typename OutT>
__global__ __launch_bounds__(256, 2)
void gemm_bt(const unsigned short* __restrict__ A, int lda, long long sA,
             const unsigned short* __restrict__ B, int ldb, long long sB,
             OutT* __restrict__ Cp, int ldc, long long sC,
             int K, float alpha, int tri, int kcap, int gx, int qkv) {
  A  += (long long)blockIdx.z * sA;
  B  += (long long)blockIdx.z * sB;
  Cp += (long long)blockIdx.z * sC;

  int by, bx;
  if (tri) {
    const int idx = blockIdx.x;
    by = (int)((sqrtf(8.f * idx + 1.f) - 1.f) * 0.5f);
    while (by * (by + 1) / 2 > idx) --by;
    while ((by + 1) * (by + 2) / 2 <= idx) ++by;
    bx = idx - by * (by + 1) / 2;
  } else if (gx > 0) {
    const int id = blockIdx.x;
    const int gs = gx * 8;
    const int g = id / gs, r = id - g * gs;
    bx = r >> 3;
    by = g * 8 + (r & 7);
  } else {
    by = blockIdx.y;
    bx = blockIdx.x;
  }
  const int m0 = by * 128;
  const int n0 = bx * 128;
  const int Keff = kcap ? min(K, m0 + 128) : K;

  const int tid  = threadIdx.x;
  const int lane = tid & 63;
  const int w    = tid >> 6;
  const int wm   = (w >> 1) * 64;
  const int wn   = (w & 1) * 64;
  const int quad = lane >> 4;
  const int l16  = lane & 15;

  __shared__ unsigned short As[128 * 64];
  __shared__ unsigned short Bs[128 * 64];

  f32x4 acc[4][4];
#pragma unroll
  for (int i = 0; i < 4; ++i)
#pragma unroll
    for (int j = 0; j < 4; ++j)
      acc[i][j] = (f32x4){0.f, 0.f, 0.f, 0.f};

  const int srow = tid >> 3;
  const int scol = ((tid & 7) ^ (srow & 7)) * 8;
  const unsigned short* gA = A + (long long)(m0 + srow) * lda + scol;
  const unsigned short* gB = B + (long long)(n0 + srow) * ldb + scol;
  const int rsw = l16 & 7;

  for (int kt = 0; kt < Keff; kt += 64) {
    __syncthreads();
#pragma unroll
    for (int r = 0; r < 4; ++r) {
      GLDS(gA + (long long)(r * 32) * lda + kt, As + r * 2048 + tid * 8);
      GLDS(gB + (long long)(r * 32) * ldb + kt, Bs + r * 2048 + tid * 8);
    }
    __syncthreads();
#pragma unroll
    for (int ks = 0; ks < 2; ++ks) {
      bf16x8 af[4], bfr[4];
#pragma unroll
      for (int i = 0; i < 4; ++i)
        af[i] = *(const bf16x8*)(As + (wm + i * 16 + l16) * 64 +
                                 ((ks * 4 + quad) ^ rsw) * 8);
#pragma unroll
      for (int j = 0; j < 4; ++j)
        bfr[j] = *(const bf16x8*)(Bs + (wn + j * 16 + l16) * 64 +
                                  ((ks * 4 + quad) ^ rsw) * 8);
#pragma unroll
      for (int i = 0; i < 4; ++i)
#pragma unroll
        for (int j = 0; j < 4; ++j)
          acc[i][j] = __builtin_amdgcn_mfma_f32_16x16x32_bf16(af[i], bfr[j],
                                                              acc[i][j], 0, 0, 0);
    }
  }

  // C/D layout (m89/m91 verified): col = lane&15, row = quad*4 + reg
#pragma unroll
  for (int i = 0; i < 4; ++i) {
#pragma unroll
    for (int j = 0; j < 4; ++j) {
      const int row = m0 + wm + i * 16 + quad * 4;
      const int col = n0 + wn + j * 16 + l16;
      if constexpr (sizeof(OutT) == 2) {
        if (qkv) {
          if (col >= 2048) {  // V, stored transposed: Vt[b][c][t]
            const int b = row >> 11, t = row & 2047, cv = col - 2048;
            ushort4 o = make_ushort4(f2bf(acc[i][j][0]), f2bf(acc[i][j][1]),
                                     f2bf(acc[i][j][2]), f2bf(acc[i][j][3]));
            *(ushort4*)((unsigned short*)Cp + 16777216LL +
                        ((long long)(b * 1024 + cv)) * 2048 + t) = o;
          } else {  // Q (col<1024) or K (col in [1024,2048))
            unsigned short* dst =
                (unsigned short*)Cp + (col >= 1024 ? 8388608LL - 1024 : 0);
#pragma unroll
            for (int r = 0; r < 4; ++r)
              dst[(long long)(row + r) * 1024 + col] = f2bf(acc[i][j][r]);
          }
          continue;
        }
#pragma unroll
        for (int r = 0; r < 4; ++r)
          Cp[(long long)(row + r) * ldc + col] = (OutT)f2bf(acc[i][j][r] * alpha);
      } else {
#pragma unroll
        for (int r = 0; r < 4; ++r)
          Cp[(long long)(row + r) * ldc + col] = acc[i][j][r] * alpha;
      }
    }
  }
}

// ------------------------- causal softmax (in place) -----------------------
__global__ __launch_bounds__(256)
void softmax_causal(unsigned short* __restrict__ S, int T) {
  const long long row = blockIdx.x;
  const int t = (int)(row & (long long)(T - 1));
  const int limit = ((t >> 7) + 1) << 7;
  unsigned short* p = S + row * T;
  const int tid  = threadIdx.x;
  const int base = tid * 8;
  const bool active = base < limit;

  short8 raw = {};
  if (active) raw = *(const short8*)(p + base);
  float x[8];
  float mx = -1e30f;
#pragma unroll
  for (int j = 0; j < 8; ++j) {
    bool valid = active && (base + j) <= t;
    x[j] = valid ? bf2f((unsigned short)raw[j]) : -1e30f;
    mx = fmaxf(mx, x[j]);
  }
#pragma unroll
  for (int off = 32; off > 0; off >>= 1) mx = fmaxf(mx, __shfl_xor(mx, off));
  __shared__ float red[8];
  const int wv = tid >> 6;
  if ((tid & 63) == 0) red[wv] = mx;
  __syncthreads();
  mx = fmaxf(fmaxf(red[0], red[1]), fmaxf(red[2], red[3]));

  float sum = 0.f;
#pragma unroll
  for (int j = 0; j < 8; ++j) {
    bool valid = active && (base + j) <= t;
    x[j] = valid ? __expf(x[j] - mx) : 0.f;
    sum += x[j];
  }
#pragma unroll
  for (int off = 32; off > 0; off >>= 1) sum += __shfl_xor(sum, off);
  if ((tid & 63) == 0) red[4 + wv] = sum;
  __syncthreads();
  sum = red[4] + red[5] + red[6] + red[7];
  const float inv = 1.f / sum;

  if (active) {
    unsigned short out[8];
#pragma unroll
    for (int j = 0; j < 8; ++j) out[j] = f2bf(x[j] * inv);
    *(short8*)(p + base) = *(const short8*)out;
  }
}

// ---------------------------------------------------------------------------
extern "C" void kernel_launch(void* const* d_in, const int* in_sizes, int n_in,
                              void* d_out, int out_size, void* d_ws,
                              size_t ws_size, hipStream_t stream) {
  (void)in_sizes; (void)n_in; (void)out_size; (void)ws_size;
  const int Bb = 4, T = 2048, C = 1024;
  const int M = Bb * T;  // 8192

  const float* X  = (const float*)d_in[0];
  const float* Wq = (const float*)d_in[1];
  const float* Wk = (const float*)d_in[2];
  const float* Wv = (const float*)d_in[3];
  const float* Wo = (const float*)d_in[4];
  float* Out = (float*)d_out;

  char* w = (char*)d_ws;
  unsigned short* Xb   = (unsigned short*)w; w += (size_t)M * C * 2;      // 16MB
  unsigned short* Wcat = (unsigned short*)w; w += (size_t)3 * C * C * 2;  // 6MB
  unsigned short* Wot  = (unsigned short*)w; w += (size_t)C * C * 2;      // 2MB
  unsigned short* Q    = (unsigned short*)w; w += (size_t)M * C * 2;      // 16MB
  unsigned short* Kb   = (unsigned short*)w; w += (size_t)M * C * 2;      // 16MB (Q+8M)
  unsigned short* Vt   = (unsigned short*)w; w += (size_t)M * C * 2;      // 16MB (Q+16M)
  unsigned short* O    = Xb;                     // Xb dead after QKV GEMM
  unsigned short* S    = (unsigned short*)d_out; // 32MB, dead before final GEMM

  cast_kernel<<<(M * C) / 4 / 256, 256, 0, stream>>>(X, Xb, M * C);
  transpose4<<<dim3(C / 32, C / 32, 4), dim3(32, 8), 0, stream>>>(
      Wq, Wk, Wv, Wo, Wcat, Wot, C);

  dim3 blk(256);
  // fused QKV: [8192 x 3072] = Xb @ Wcat^T-layout; V transposed in epilogue
  gemm_bt<unsigned short><<<dim3((3 * C / 128) * (M / 128), 1, 1), blk, 0, stream>>>(
      Xb, C, 0, Wcat, C, 0, Q, C, 0, C, 1.f, 0, 0, /*gx=*/3 * C / 128, /*qkv=*/1);
  // S[b] = Q[b] @ K[b]^T / 32 — lower-triangle tiles only
  const int ntri = (T / 128) * (T / 128 + 1) / 2;
  gemm_bt<unsigned short><<<dim3(ntri, 1, Bb), blk, 0, stream>>>(
      Q, C, (long long)T * C, Kb, C, (long long)T * C,
      S, T, (long long)T * T, C, 0.03125f, 1, 0, 0, 0);
  // causal softmax (row-truncated)
  softmax_causal<<<M, 256, 0, stream>>>(S, T);
  // O[b] = P[b] @ V[b] with causal K-cap
  gemm_bt<unsigned short><<<dim3((C / 128) * (T / 128), 1, Bb), blk, 0, stream>>>(
      S, T, (long long)T * T, Vt, T, (long long)C * T,
      O, C, (long long)T * C, T, 1.f, 0, 1, /*gx=*/C / 128, 0);
  // Out = O @ Wo (fp32 epilogue)
  gemm_bt<float><<<dim3((C / 128) * (M / 128), 1, 1), blk, 0, stream>>>(
      O, C, 0, Wot, C, 0, Out, C, 0, C, 1.f, 0, 0, /*gx=*/C / 128, 0);
}